// Round 3
// baseline (4699.947 us; speedup 1.0000x reference)
//
#include <hip/hip_runtime.h>
#include <hip/hip_bf16.h>
#include <stdint.h>

#define BATCH 32
#define SEQT  512
#define DIM   256
#define UU    512
#define WGL   32          // workgroups per layer (each: 16 units x 32 rows)

typedef __attribute__((ext_vector_type(8))) short bf16x8;
typedef __attribute__((ext_vector_type(4))) float f32x4;

__device__ __forceinline__ short f2bf(float f) {
  uint32_t u = __builtin_bit_cast(uint32_t, f);
  u += 0x7FFFu + ((u >> 16) & 1u);   // RNE
  return (short)(u >> 16);
}

__device__ __forceinline__ float sigm(float x) { return 1.0f / (1.0f + __expf(-x)); }

__device__ __forceinline__ float tanh_fast(float x) {
  float ax = fabsf(x);
  float t = __expf(-2.0f * ax);
  float r = (1.0f - t) / (1.0f + t);
  return copysignf(r, x);
}

// write-through store visible at the device coherence point once vmcnt drains
__device__ __forceinline__ void store_u32_sc01(int* p, uint32_t v) {
  asm volatile("global_store_dword %0, %1, off sc0 sc1" :: "v"(p), "v"(v) : "memory");
}
__device__ __forceinline__ void store_short_sc01(short* p, short v) {
  uint32_t d = (uint16_t)v;
  asm volatile("global_store_short %0, %1, off sc0 sc1" :: "v"(p), "v"(d) : "memory");
}
__device__ __forceinline__ int load_int_sc01(const int* p) {
  int v;
  asm volatile("global_load_dword %0, %1, off sc0 sc1\n\ts_waitcnt vmcnt(0)"
               : "=v"(v) : "v"(p) : "memory");
  return v;
}

// One layer's persistent scan. 32 WGs/layer; WG jblk owns units [16*jblk,16*jblk+16),
// all 4 gates (wave = gate), all 32 batch rows. Weights live in registers.
template<int XSTEPS, bool XF32>
__device__ void scan_body(
    int jblk,
    const float* __restrict__ xf,       // [B][T][D] (layer 0 only)
    const short* __restrict__ Hprev,    // bf16 [T+1][32][512]
    short*       __restrict__ Hcur,     // bf16 [T+1][32][512]
    const float* __restrict__ W,        // [KX][2048]
    const float* __restrict__ R,        // [512][2048]
    const float* __restrict__ bias,     // [2048]
    const float* __restrict__ hinit,    // [512]
    const float* __restrict__ cinit,    // [512]
    const int* progPrev, int* progOwn)  // 32 watermark words each
{
  const int tid  = threadIdx.x;
  const int g    = tid >> 6;            // wave = gate (i,f,g,o)
  const int lane = tid & 63;
  const int arow = lane & 15;           // MFMA A row / B col
  const int kq   = lane >> 4;
  const int jbase = jblk * 16;
  const int colg  = g * UU + jbase + arow;

  // one-time: weight B-fragments into registers for the whole scan
  bf16x8 bw[XSTEPS];
  bf16x8 br[16];
#pragma unroll
  for (int ks = 0; ks < XSTEPS; ++ks) {
    bf16x8 v;
#pragma unroll
    for (int jj = 0; jj < 8; ++jj)
      v[jj] = f2bf(W[(size_t)(ks * 32 + kq * 8 + jj) * 2048 + colg]);
    bw[ks] = v;
  }
#pragma unroll
  for (int ks = 0; ks < 16; ++ks) {
    bf16x8 v;
#pragma unroll
    for (int jj = 0; jj < 8; ++jj)
      v[jj] = f2bf(R[(size_t)(ks * 32 + kq * 8 + jj) * 2048 + colg]);
    br[ks] = v;
  }

  // epilogue mapping: thread -> (row erow) x (unit pair epair)
  const int epair = tid & 7;            // unit pair: units 2*epair, 2*epair+1
  const int erow  = tid >> 3;           // 0..31
  const int u0 = 2 * epair, u1 = 2 * epair + 1;
  float biasv[4][2];
#pragma unroll
  for (int gg = 0; gg < 4; ++gg) {
    biasv[gg][0] = bias[gg * UU + jbase + u0];
    biasv[gg][1] = bias[gg * UU + jbase + u1];
  }
  float cr0 = cinit[jbase + u0];
  float cr1 = cinit[jbase + u1];

  // init tile H[0] = tile(h_init), one packed dword per thread
  {
    uint32_t pk = ((uint32_t)(uint16_t)f2bf(hinit[jbase + u1]) << 16)
                |  (uint16_t)f2bf(hinit[jbase + u0]);
    store_u32_sc01((int*)(Hcur + (size_t)erow * UU + jbase + u0), pk);
  }
  asm volatile("s_waitcnt vmcnt(0)" ::: "memory");
  __syncthreads();
  if (tid == 0) store_u32_sc01(progOwn + jblk, 1);   // prog >= t+1 <=> H[t] ready

  // per-lane poll assignment: lanes 0..31 own line, 32..63 prev line
  const int* pollPtr;
  int needOff;
  if (lane < 32)      { pollPtr = progOwn  + lane;        needOff = 1; }
  else if (XF32)      { pollPtr = progOwn  + (lane - 32); needOff = 1; }
  else                { pollPtr = progPrev + (lane - 32); needOff = 2; }

  __shared__ float zsm[4][32][16];

#pragma unroll 1
  for (int t = 0; t < SEQT; ++t) {
    if (g == 0) {
      const int need = t + needOff;
      while (true) {
        int v = load_int_sc01(pollPtr);
        if (__all(v >= need)) break;
        __builtin_amdgcn_s_sleep(1);
      }
    }
    __syncthreads();

    f32x4 acc0 = {0.f, 0.f, 0.f, 0.f};
    f32x4 acc1 = {0.f, 0.f, 0.f, 0.f};

    // x @ W
    if constexpr (XF32) {
      const float* p0 = xf + ((size_t)arow * SEQT + t) * DIM + kq * 8;
      const float* p1 = xf + ((size_t)(arow + 16) * SEQT + t) * DIM + kq * 8;
#pragma unroll
      for (int ks = 0; ks < XSTEPS; ++ks) {
        float4 x0 = *(const float4*)(p0 + ks * 32);
        float4 x1 = *(const float4*)(p0 + ks * 32 + 4);
        float4 y0 = *(const float4*)(p1 + ks * 32);
        float4 y1 = *(const float4*)(p1 + ks * 32 + 4);
        bf16x8 a0, a1;
        a0[0] = f2bf(x0.x); a0[1] = f2bf(x0.y); a0[2] = f2bf(x0.z); a0[3] = f2bf(x0.w);
        a0[4] = f2bf(x1.x); a0[5] = f2bf(x1.y); a0[6] = f2bf(x1.z); a0[7] = f2bf(x1.w);
        a1[0] = f2bf(y0.x); a1[1] = f2bf(y0.y); a1[2] = f2bf(y0.z); a1[3] = f2bf(y0.w);
        a1[4] = f2bf(y1.x); a1[5] = f2bf(y1.y); a1[6] = f2bf(y1.z); a1[7] = f2bf(y1.w);
        acc0 = __builtin_amdgcn_mfma_f32_16x16x32_bf16(a0, bw[ks], acc0, 0, 0, 0);
        acc1 = __builtin_amdgcn_mfma_f32_16x16x32_bf16(a1, bw[ks], acc1, 0, 0, 0);
      }
    } else {
      const short* xp = Hprev + (size_t)(t + 1) * BATCH * UU + kq * 8;
#pragma unroll
      for (int ks = 0; ks < XSTEPS; ++ks) {
        bf16x8 a0 = *(const bf16x8*)(xp + (size_t)arow * UU + ks * 32);
        bf16x8 a1 = *(const bf16x8*)(xp + (size_t)(arow + 16) * UU + ks * 32);
        acc0 = __builtin_amdgcn_mfma_f32_16x16x32_bf16(a0, bw[ks], acc0, 0, 0, 0);
        acc1 = __builtin_amdgcn_mfma_f32_16x16x32_bf16(a1, bw[ks], acc1, 0, 0, 0);
      }
    }

    // h @ R
    const short* hp = Hcur + (size_t)t * BATCH * UU + kq * 8;
#pragma unroll
    for (int ks = 0; ks < 16; ++ks) {
      bf16x8 a0 = *(const bf16x8*)(hp + (size_t)arow * UU + ks * 32);
      bf16x8 a1 = *(const bf16x8*)(hp + (size_t)(arow + 16) * UU + ks * 32);
      acc0 = __builtin_amdgcn_mfma_f32_16x16x32_bf16(a0, br[ks], acc0, 0, 0, 0);
      acc1 = __builtin_amdgcn_mfma_f32_16x16x32_bf16(a1, br[ks], acc1, 0, 0, 0);
    }

    // exchange z across waves (gates live in different waves)
#pragma unroll
    for (int r = 0; r < 4; ++r) {
      zsm[g][kq * 4 + r][arow]      = acc0[r];
      zsm[g][16 + kq * 4 + r][arow] = acc1[r];
    }
    __syncthreads();

    // gates + state (fp32), write h as one packed dword (visible at L3)
    {
      float zi0 = zsm[0][erow][u0] + biasv[0][0];
      float zf0 = zsm[1][erow][u0] + biasv[1][0];
      float zg0 = zsm[2][erow][u0] + biasv[2][0];
      float zo0 = zsm[3][erow][u0] + biasv[3][0];
      float zi1 = zsm[0][erow][u1] + biasv[0][1];
      float zf1 = zsm[1][erow][u1] + biasv[1][1];
      float zg1 = zsm[2][erow][u1] + biasv[2][1];
      float zo1 = zsm[3][erow][u1] + biasv[3][1];
      cr0 = sigm(zf0) * cr0 + sigm(zi0) * tanh_fast(zg0);
      cr1 = sigm(zf1) * cr1 + sigm(zi1) * tanh_fast(zg1);
      float h0 = sigm(zo0) * tanh_fast(cr0);
      float h1 = sigm(zo1) * tanh_fast(cr1);
      uint32_t pk = ((uint32_t)(uint16_t)f2bf(h1) << 16) | (uint16_t)f2bf(h0);
      store_u32_sc01((int*)(Hcur + ((size_t)(t + 1) * BATCH + erow) * UU + jbase + u0), pk);
    }
    asm volatile("s_waitcnt vmcnt(0)" ::: "memory");   // own stores acked
    __syncthreads();                                   // all waves' stores acked
    if (tid == 0) store_u32_sc01(progOwn + jblk, t + 2);
  }
}

__global__ __launch_bounds__(256, 1) void lstm_scan(
    const float* __restrict__ inputs,
    const float* __restrict__ W0, const float* __restrict__ R0, const float* __restrict__ b0,
    const float* __restrict__ h0i, const float* __restrict__ c0i,
    const float* __restrict__ W1, const float* __restrict__ R1, const float* __restrict__ b1,
    const float* __restrict__ h1i, const float* __restrict__ c1i,
    const float* __restrict__ W2, const float* __restrict__ R2, const float* __restrict__ b2,
    const float* __restrict__ h2i, const float* __restrict__ c2i,
    short* __restrict__ H0, short* __restrict__ H1, short* __restrict__ H2,
    int* flags)
{
  const int layer = blockIdx.x / WGL;
  const int jblk  = blockIdx.x % WGL;
  int* p0 = flags;          // 512B-spaced watermark lines
  int* p1 = flags + 128;
  int* p2 = flags + 256;
  if (layer == 0)
    scan_body<8,  true >(jblk, inputs, nullptr, H0, W0, R0, b0, h0i, c0i, nullptr, p0);
  else if (layer == 1)
    scan_body<16, false>(jblk, nullptr, H0, H1, W1, R1, b1, h1i, c1i, p0, p1);
  else
    scan_body<16, false>(jblk, nullptr, H1, H2, W2, R2, b2, h2i, c2i, p1, p2);
}

// Y[b][t][:] = H2[t+1][b][:] @ Wd + bd.  Tile: 128 rows x 64 cols per WG.
__global__ __launch_bounds__(256, 2) void dense_out(
    const short* __restrict__ H2,      // [T+1][32][512]
    const float* __restrict__ Wd,      // [512][256]
    const float* __restrict__ bd,      // [256]
    float* __restrict__ out)           // [32][512][256]
{
  const int mblock = blockIdx.x;       // 0..127
  const int nblock = blockIdx.y;       // 0..3
  const int tid  = threadIdx.x;
  const int wave = tid >> 6;
  const int lane = tid & 63;
  const int col  = lane & 15;
  const int kq   = lane >> 4;

  __shared__ short wlds[64][264];      // transposed Wd slice (half-K), padded

  f32x4 acc[2][4];
#pragma unroll
  for (int mi = 0; mi < 2; ++mi)
#pragma unroll
    for (int ni = 0; ni < 4; ++ni)
      acc[mi][ni] = f32x4{0.f, 0.f, 0.f, 0.f};

  const short* Abase = H2 + (size_t)32 * UU;   // skip the init tile

  for (int half = 0; half < 2; ++half) {
    __syncthreads();
    for (int idx = tid; idx < 256 * 64; idx += 256) {
      int k = idx >> 6;
      int c = idx & 63;
      wlds[c][k] = f2bf(Wd[(size_t)(half * 256 + k) * 256 + nblock * 64 + c]);
    }
    __syncthreads();
#pragma unroll
    for (int ks = 0; ks < 8; ++ks) {
      const int d0g = half * 256 + ks * 32 + kq * 8;
      const int d0l = ks * 32 + kq * 8;
      const size_t r0 = (size_t)(mblock * 128 + wave * 32 + col) * UU;
      const size_t r1 = (size_t)(mblock * 128 + wave * 32 + 16 + col) * UU;
      bf16x8 a0 = *(const bf16x8*)(Abase + r0 + d0g);
      bf16x8 a1 = *(const bf16x8*)(Abase + r1 + d0g);
#pragma unroll
      for (int ni = 0; ni < 4; ++ni) {
        bf16x8 bv = *(const bf16x8*)(&wlds[ni * 16 + col][d0l]);
        acc[0][ni] = __builtin_amdgcn_mfma_f32_16x16x32_bf16(a0, bv, acc[0][ni], 0, 0, 0);
        acc[1][ni] = __builtin_amdgcn_mfma_f32_16x16x32_bf16(a1, bv, acc[1][ni], 0, 0, 0);
      }
    }
  }

#pragma unroll
  for (int ni = 0; ni < 4; ++ni) {
    float bdv = bd[nblock * 64 + ni * 16 + col];
#pragma unroll
    for (int mi = 0; mi < 2; ++mi) {
#pragma unroll
      for (int r = 0; r < 4; ++r) {
        int grow = mblock * 128 + wave * 32 + mi * 16 + kq * 4 + r;
        int t = grow >> 5, b = grow & 31;
        out[((size_t)b * SEQT + t) * DIM + nblock * 64 + ni * 16 + col] = acc[mi][ni][r] + bdv;
      }
    }
  }
}

extern "C" void kernel_launch(void* const* d_in, const int* in_sizes, int n_in,
                              void* d_out, int out_size, void* d_ws, size_t ws_size,
                              hipStream_t stream) {
  const float* inputs = (const float*)d_in[0];
  const float* W0 = (const float*)d_in[1];
  const float* R0 = (const float*)d_in[2];
  const float* b0 = (const float*)d_in[3];
  const float* h0 = (const float*)d_in[4];
  const float* c0 = (const float*)d_in[5];
  const float* W1 = (const float*)d_in[6];
  const float* R1 = (const float*)d_in[7];
  const float* b1 = (const float*)d_in[8];
  const float* h1 = (const float*)d_in[9];
  const float* c1 = (const float*)d_in[10];
  const float* W2 = (const float*)d_in[11];
  const float* R2 = (const float*)d_in[12];
  const float* b2 = (const float*)d_in[13];
  const float* h2 = (const float*)d_in[14];
  const float* c2 = (const float*)d_in[15];
  const float* Wd = (const float*)d_in[16];
  const float* bd = (const float*)d_in[17];

  int* flags = (int*)d_ws;
  char* base = (char*)d_ws + 4096;
  size_t Hbytes = (size_t)(SEQT + 1) * BATCH * UU * sizeof(short);  // ~16.8 MB
  short* H0 = (short*)(base);
  short* H1 = (short*)(base + Hbytes);
  short* H2 = (short*)(base + 2 * Hbytes);

  hipMemsetAsync(d_ws, 0, 4096, stream);   // watermark words = 0 (nothing ready)

  hipLaunchKernelGGL(lstm_scan, dim3(3 * WGL), dim3(256), 0, stream,
                     inputs, W0, R0, b0, h0, c0, W1, R1, b1, h1, c1,
                     W2, R2, b2, h2, c2, H0, H1, H2, flags);

  hipLaunchKernelGGL(dense_out, dim3(128, 4), dim3(256), 0, stream,
                     H2, Wd, bd, (float*)d_out);
}